// Round 1
// baseline (868.792 us; speedup 1.0000x reference)
//
#include <hip/hip_runtime.h>

#define N_TOK 4096
#define C_DIM 256
#define CQ    32
#define TQ    64
#define TJ    32
#define LOG2E 1.44269504088896f

// ---------------------------------------------------------------------------
// Projection: Y[b][m][n] = sum_c W[m][c] * x[b][c][n] + bias[m]
// grid: (N/64, M/32, B), block 256
// ---------------------------------------------------------------------------
__global__ __launch_bounds__(256, 2)
void proj_kernel(const float* __restrict__ x, const float* __restrict__ Wt,
                 const float* __restrict__ bias, float* __restrict__ y, int M) {
    __shared__ float xs[64][68];
    __shared__ float wsm[32][68];
    const int b  = blockIdx.z;
    const int m0 = blockIdx.y * 32;
    const int n0 = blockIdx.x * 64;
    const int t  = threadIdx.x;
    const float* xb = x + (size_t)b * C_DIM * N_TOK;

    float acc[8];
#pragma unroll
    for (int i = 0; i < 8; i++) acc[i] = 0.f;

    const int n  = t & 63;
    const int mg = t >> 6;   // 0..3

    for (int kc = 0; kc < C_DIM; kc += 64) {
        // x chunk: 64 c-rows x 64 tokens
#pragma unroll
        for (int r = 0; r < 16; r++) {
            int idx = t + r * 256;
            int c = idx >> 6, nn = idx & 63;
            xs[c][nn] = xb[(size_t)(kc + c) * N_TOK + n0 + nn];
        }
        // W chunk: 32 m-rows x 64 c
#pragma unroll
        for (int r = 0; r < 8; r++) {
            int idx = t + r * 256;
            int m = idx >> 6, cc = idx & 63;
            wsm[m][cc] = Wt[(size_t)(m0 + m) * C_DIM + kc + cc];
        }
        __syncthreads();
#pragma unroll 8
        for (int c = 0; c < 64; c++) {
            float xv = xs[c][n];
#pragma unroll
            for (int mm = 0; mm < 8; mm++)
                acc[mm] = fmaf(wsm[mg * 8 + mm][c], xv, acc[mm]);
        }
        __syncthreads();
    }
#pragma unroll
    for (int mm = 0; mm < 8; mm++) {
        int m = m0 + mg * 8 + mm;
        y[((size_t)b * M + m) * N_TOK + n0 + n] = acc[mm] + bias[m];
    }
}

// ---------------------------------------------------------------------------
// Fused attention: per block, 64 queries of one batch, flash-style over all
// 4096 keys in tiles of 32.  Q/K layout [B][32][N], V layout [B][256][N].
// out[b][c][i] = (sum_j exp(s_ij - m_i) V[c][j]) / l_i + x[b][c][i]
// ---------------------------------------------------------------------------
__global__ __launch_bounds__(256, 2)
void attn_kernel(const float* __restrict__ Q, const float* __restrict__ K,
                 const float* __restrict__ V, const float* __restrict__ x,
                 float* __restrict__ out) {
    __shared__ float lq[CQ][TQ + 4];      // [32][68]
    __shared__ float lk[CQ][TJ + 4];      // [32][36]
    __shared__ float lv[TJ][C_DIM + 4];   // [32][260] (j-major, transposed)
    __shared__ float lp[TQ][33];          // scores / probabilities
    __shared__ float lm[TQ], ll[TQ], lf[TQ];

    const int b  = blockIdx.y;
    const int i0 = blockIdx.x * TQ;
    const int t  = threadIdx.x;
    const float* Qb = Q + (size_t)b * CQ * N_TOK;
    const float* Kb = K + (size_t)b * CQ * N_TOK;
    const float* Vb = V + (size_t)b * C_DIM * N_TOK;

    // load Q tile once: 32 d x 64 q
#pragma unroll
    for (int r = 0; r < 8; r++) {
        int idx = t + r * 256;
        int d = idx >> 6, q = idx & 63;
        lq[d][q] = Qb[(size_t)d * N_TOK + i0 + q];
    }
    if (t < TQ) { lm[t] = -1e30f; ll[t] = 0.f; }

    float acc[8][8];
#pragma unroll
    for (int i = 0; i < 8; i++)
#pragma unroll
        for (int j = 0; j < 8; j++) acc[i][j] = 0.f;

    // thread mappings
    const int sq0 = (t >> 4) * 4;   // scores: 4 q
    const int sj0 = (t & 15) * 2;   // scores: 2 j
    const int er  = t >> 2;         // exp pass: row
    const int ej0 = (t & 3) * 8;    // exp pass: 8 j
    const int pq0 = (t >> 5) * 8;   // pv: 8 q
    const int pc0 = (t & 31) * 8;   // pv: 8 c

    for (int j0 = 0; j0 < N_TOK; j0 += TJ) {
        // ---- load K tile (32 d x 32 j) and V tile transposed (32 j x 256 c)
#pragma unroll
        for (int r = 0; r < 4; r++) {
            int idx = t + r * 256;
            int d = idx >> 5, j = idx & 31;
            lk[d][j] = Kb[(size_t)d * N_TOK + j0 + j];
        }
#pragma unroll
        for (int r = 0; r < 32; r++) {
            int idx = t + r * 256;
            int c = idx >> 5, j = idx & 31;
            lv[j][c] = Vb[(size_t)c * N_TOK + j0 + j];
        }
        __syncthreads();

        // ---- scores: S[q][j], 4q x 2j per thread
        float s[4][2];
#pragma unroll
        for (int qq = 0; qq < 4; qq++) { s[qq][0] = 0.f; s[qq][1] = 0.f; }
#pragma unroll 4
        for (int d = 0; d < CQ; d++) {
            float4 qv = *(const float4*)&lq[d][sq0];
            float k0 = lk[d][sj0], k1 = lk[d][sj0 + 1];
            s[0][0] = fmaf(qv.x, k0, s[0][0]); s[0][1] = fmaf(qv.x, k1, s[0][1]);
            s[1][0] = fmaf(qv.y, k0, s[1][0]); s[1][1] = fmaf(qv.y, k1, s[1][1]);
            s[2][0] = fmaf(qv.z, k0, s[2][0]); s[2][1] = fmaf(qv.z, k1, s[2][1]);
            s[3][0] = fmaf(qv.w, k0, s[3][0]); s[3][1] = fmaf(qv.w, k1, s[3][1]);
        }
#pragma unroll
        for (int qq = 0; qq < 4; qq++) {
            lp[sq0 + qq][sj0]     = s[qq][0];
            lp[sq0 + qq][sj0 + 1] = s[qq][1];
        }
        __syncthreads();

        // ---- online softmax: 4 lanes per row, 8 j each
        float mold = lm[er];
        float sv[8];
        float tmax = -1e30f;
#pragma unroll
        for (int jj = 0; jj < 8; jj++) {
            sv[jj] = lp[er][ej0 + jj];
            tmax = fmaxf(tmax, sv[jj]);
        }
        tmax = fmaxf(tmax, __shfl_xor(tmax, 1));
        tmax = fmaxf(tmax, __shfl_xor(tmax, 2));
        float mnew = fmaxf(mold, tmax);
        float psum = 0.f;
#pragma unroll
        for (int jj = 0; jj < 8; jj++) {
            float p = exp2f((sv[jj] - mnew) * LOG2E);
            lp[er][ej0 + jj] = p;
            psum += p;
        }
        psum += __shfl_xor(psum, 1);
        psum += __shfl_xor(psum, 2);
        if ((t & 3) == 0) {
            float f = exp2f((mold - mnew) * LOG2E);
            lf[er] = f;
            lm[er] = mnew;
            ll[er] = ll[er] * f + psum;
        }
        __syncthreads();

        // ---- rescale accumulators, then PV: acc[q][c] += P[q][j]*V[c][j]
        float f[8];
#pragma unroll
        for (int qq = 0; qq < 8; qq++) f[qq] = lf[pq0 + qq];
#pragma unroll
        for (int qq = 0; qq < 8; qq++)
#pragma unroll
            for (int cc = 0; cc < 8; cc++) acc[qq][cc] *= f[qq];

#pragma unroll 2
        for (int j = 0; j < TJ; j++) {
            float pr[8];
#pragma unroll
            for (int qq = 0; qq < 8; qq++) pr[qq] = lp[pq0 + qq][j];
            float4 v0 = *(const float4*)&lv[j][pc0];
            float4 v1 = *(const float4*)&lv[j][pc0 + 4];
            float vr[8] = {v0.x, v0.y, v0.z, v0.w, v1.x, v1.y, v1.z, v1.w};
#pragma unroll
            for (int qq = 0; qq < 8; qq++)
#pragma unroll
                for (int cc = 0; cc < 8; cc++)
                    acc[qq][cc] = fmaf(pr[qq], vr[cc], acc[qq][cc]);
        }
        __syncthreads();
    }

    // ---- epilogue: /l, +x, store
    float linv[8];
#pragma unroll
    for (int qq = 0; qq < 8; qq++) linv[qq] = 1.f / ll[pq0 + qq];

#pragma unroll
    for (int cc = 0; cc < 8; cc++) {
        const int c = pc0 + cc;
        const size_t base = ((size_t)b * C_DIM + c) * N_TOK + i0 + pq0;
        float4 x0 = *(const float4*)&x[base];
        float4 x1 = *(const float4*)&x[base + 4];
        float4 o0, o1;
        o0.x = fmaf(acc[0][cc], linv[0], x0.x);
        o0.y = fmaf(acc[1][cc], linv[1], x0.y);
        o0.z = fmaf(acc[2][cc], linv[2], x0.z);
        o0.w = fmaf(acc[3][cc], linv[3], x0.w);
        o1.x = fmaf(acc[4][cc], linv[4], x1.x);
        o1.y = fmaf(acc[5][cc], linv[5], x1.y);
        o1.z = fmaf(acc[6][cc], linv[6], x1.z);
        o1.w = fmaf(acc[7][cc], linv[7], x1.w);
        *(float4*)&out[base]     = o0;
        *(float4*)&out[base + 4] = o1;
    }
}

// ---------------------------------------------------------------------------
extern "C" void kernel_launch(void* const* d_in, const int* in_sizes, int n_in,
                              void* d_out, int out_size, void* d_ws, size_t ws_size,
                              hipStream_t stream) {
    const float* x  = (const float*)d_in[0];
    const float* Wq = (const float*)d_in[1];
    const float* bq = (const float*)d_in[2];
    const float* Wk = (const float*)d_in[3];
    const float* bk = (const float*)d_in[4];
    const float* Wv = (const float*)d_in[5];
    const float* bv = (const float*)d_in[6];
    float* out = (float*)d_out;

    const int B = 4;
    float* q_ws = (float*)d_ws;                       // [B][32][N]
    float* k_ws = q_ws + (size_t)B * CQ * N_TOK;      // [B][32][N]
    float* v_ws = k_ws + (size_t)B * CQ * N_TOK;      // [B][256][N]

    dim3 blk(256);
    proj_kernel<<<dim3(N_TOK / 64, CQ / 32, B), blk, 0, stream>>>(x, Wq, bq, q_ws, CQ);
    proj_kernel<<<dim3(N_TOK / 64, CQ / 32, B), blk, 0, stream>>>(x, Wk, bk, k_ws, CQ);
    proj_kernel<<<dim3(N_TOK / 64, C_DIM / 32, B), blk, 0, stream>>>(x, Wv, bv, v_ws, C_DIM);
    attn_kernel<<<dim3(N_TOK / TQ, B), blk, 0, stream>>>(q_ws, k_ws, v_ws, x, out);
}

// Round 2
// 546.591 us; speedup vs baseline: 1.5895x; 1.5895x over previous
//
#include <hip/hip_runtime.h>

typedef short short8 __attribute__((ext_vector_type(8)));
typedef float f32x4 __attribute__((ext_vector_type(4)));
typedef unsigned short u16;
typedef u16 u16x8 __attribute__((ext_vector_type(8)));

#define NTOK 4096
#define CDIM 256
#define TQ 64
#define TJ 32
#define NT (NTOK / TJ)
#define LOG2E 1.44269504088896f

__device__ __forceinline__ u16 f2bf(float f) {
    unsigned u = __float_as_uint(f);
    unsigned r = (u + 0x7fffu + ((u >> 16) & 1u)) >> 16;   // RNE
    return (u16)r;
}
__device__ __forceinline__ float bf2f(u16 h) { return __uint_as_float(((unsigned)h) << 16); }

// ---------------------------------------------------------------------------
// Q/K projection (M=32): out token-major bf16 hi/lo [B][N][32]
// grid (N/64, 2, B); y=0 -> Q, y=1 -> K
// ---------------------------------------------------------------------------
__global__ __launch_bounds__(256, 2)
void proj_qk(const float* __restrict__ x,
             const float* __restrict__ Wq, const float* __restrict__ bq,
             const float* __restrict__ Wk, const float* __restrict__ bk,
             u16* __restrict__ qhi, u16* __restrict__ qlo,
             u16* __restrict__ khi, u16* __restrict__ klo) {
    __shared__ float xs[64][68];
    __shared__ float wsm[32][68];
    const int b  = blockIdx.z;
    const int n0 = blockIdx.x * 64;
    const int isK = blockIdx.y;
    const float* W    = isK ? Wk : Wq;
    const float* bias = isK ? bk : bq;
    u16* yh = isK ? khi : qhi;
    u16* yl = isK ? klo : qlo;
    const int t  = threadIdx.x;
    const int n  = t & 63;
    const int mg = t >> 6;
    const float* xb = x + (size_t)b * CDIM * NTOK;

    float acc[8];
#pragma unroll
    for (int i = 0; i < 8; i++) acc[i] = 0.f;

    for (int kc = 0; kc < CDIM; kc += 64) {
#pragma unroll
        for (int r = 0; r < 16; r++) {
            int idx = t + r * 256;
            xs[idx >> 6][idx & 63] = xb[(size_t)(kc + (idx >> 6)) * NTOK + n0 + (idx & 63)];
        }
#pragma unroll
        for (int r = 0; r < 8; r++) {
            int idx = t + r * 256;
            wsm[idx >> 6][idx & 63] = W[(size_t)(idx >> 6) * CDIM + kc + (idx & 63)];
        }
        __syncthreads();
#pragma unroll 8
        for (int c = 0; c < 64; c++) {
            float xv = xs[c][n];
#pragma unroll
            for (int mm = 0; mm < 8; mm++)
                acc[mm] = fmaf(wsm[mg * 8 + mm][c], xv, acc[mm]);
        }
        __syncthreads();
    }
    u16x8 h8, l8;
#pragma unroll
    for (int mm = 0; mm < 8; mm++) {
        float v = acc[mm] + bias[mg * 8 + mm];
        u16 h = f2bf(v);
        h8[mm] = h;
        l8[mm] = f2bf(v - bf2f(h));
    }
    const size_t base = ((size_t)(b * NTOK + n0 + n)) * 32 + mg * 8;
    *(u16x8*)&yh[base] = h8;
    *(u16x8*)&yl[base] = l8;
}

// ---------------------------------------------------------------------------
// V projection (M=256, M-tile 64): out c-major bf16 [B][256][N]
// grid (N/64, 4, B)
// ---------------------------------------------------------------------------
__global__ __launch_bounds__(256, 2)
void proj_v(const float* __restrict__ x, const float* __restrict__ Wv,
            const float* __restrict__ bv, u16* __restrict__ vbf) {
    __shared__ float xs[64][68];
    __shared__ float wsm[64][68];
    const int b  = blockIdx.z;
    const int m0 = blockIdx.y * 64;
    const int n0 = blockIdx.x * 64;
    const int t  = threadIdx.x;
    const int n  = t & 63;
    const int mg = t >> 6;
    const float* xb = x + (size_t)b * CDIM * NTOK;

    float acc[16];
#pragma unroll
    for (int i = 0; i < 16; i++) acc[i] = 0.f;

    for (int kc = 0; kc < CDIM; kc += 64) {
#pragma unroll
        for (int r = 0; r < 16; r++) {
            int idx = t + r * 256;
            xs[idx >> 6][idx & 63] = xb[(size_t)(kc + (idx >> 6)) * NTOK + n0 + (idx & 63)];
        }
#pragma unroll
        for (int r = 0; r < 16; r++) {
            int idx = t + r * 256;
            wsm[idx >> 6][idx & 63] = Wv[(size_t)(m0 + (idx >> 6)) * CDIM + kc + (idx & 63)];
        }
        __syncthreads();
#pragma unroll 4
        for (int c = 0; c < 64; c++) {
            float xv = xs[c][n];
#pragma unroll
            for (int mm = 0; mm < 16; mm++)
                acc[mm] = fmaf(wsm[mg * 16 + mm][c], xv, acc[mm]);
        }
        __syncthreads();
    }
#pragma unroll
    for (int mm = 0; mm < 16; mm++) {
        int m = m0 + mg * 16 + mm;
        vbf[((size_t)(b * CDIM + m)) * NTOK + n0 + n] = f2bf(acc[mm] + bv[m]);
    }
}

// ---------------------------------------------------------------------------
// Fused flash attention with MFMA.
//   scores: S = Q K^T via 3 bf16 MFMAs (hi/lo split), K-dim = d = 32
//   PV:     D[i][c] += P[i][j] V[c][j], bf16 P and V
// 4 waves: wave w owns softmax of i-tile w (16 q) and PV c-quarter w (64 c).
// Double-buffered LDS K/V tiles, reg-prefetch of next tile.
// ---------------------------------------------------------------------------
__global__ __launch_bounds__(256, 1)
void attn_mfma(const u16* __restrict__ qhi, const u16* __restrict__ qlo,
               const u16* __restrict__ khi, const u16* __restrict__ klo,
               const u16* __restrict__ vbf, const float* __restrict__ x,
               float* __restrict__ out) {
    __shared__ __attribute__((aligned(16))) u16 lkh[2][TJ][32];
    __shared__ __attribute__((aligned(16))) u16 lkl[2][TJ][32];
    __shared__ __attribute__((aligned(16))) u16 lv[2][CDIM][TJ];
    __shared__ __attribute__((aligned(16))) u16 lp[4][16][TJ];
    __shared__ __attribute__((aligned(16))) float lf[4][16];
    __shared__ __attribute__((aligned(16))) float lsc[64];

    // XCD swizzle: batch b -> XCDs {2b, 2b+1}; V[b] (2MB bf16) fits one L2
    const int lin = blockIdx.x;
    const int b  = (lin >> 1) & 3;
    const int qb = ((lin & 1) << 5) | (lin >> 3);
    const int i0 = qb * TQ;
    const int t  = threadIdx.x;
    const int w  = t >> 6;
    const int l  = t & 63;
    const int cl = l & 15;
    const int kg = l >> 4;

    // Q A-fragments (this wave's i-tile = w): lane holds Q[i0+w*16+cl][kg*8 .. +8]
    const int iq = i0 + w * 16 + cl;
    const short8 qh = *(const short8*)&qhi[((size_t)(b * NTOK + iq)) * 32 + kg * 8];
    const short8 ql = *(const short8*)&qlo[((size_t)(b * NTOK + iq)) * 32 + kg * 8];

    // staging sources
    const u16* vsrc = &vbf[((size_t)(b * CDIM + t)) * NTOK];
    const int kj  = (t & 127) >> 2;
    const int kch = t & 3;
    const u16* ksrcbase = (t < 128) ? khi : klo;
    const u16* ksrc = &ksrcbase[((size_t)(b * NTOK + kj)) * 32 + kch * 8];

    u16x8 vreg[4];
    u16x8 kreg;

    auto stage_load = [&](int tt) {
        const int j0 = tt * TJ;
#pragma unroll
        for (int ch = 0; ch < 4; ch++)
            vreg[ch] = *(const u16x8*)&vsrc[j0 + ch * 8];
        kreg = *(const u16x8*)&ksrc[(size_t)j0 * 32];
    };
    auto stage_write = [&](int buf) {
#pragma unroll
        for (int ch = 0; ch < 4; ch++) {
            int ph = ch ^ ((t >> 2) & 3);       // XOR chunk swizzle (row = t)
            *(u16x8*)&lv[buf][t][ph * 8] = vreg[ch];
        }
        int ph = kch ^ ((kj >> 2) & 3);
        u16* kd = (t < 128) ? &lkh[buf][kj][ph * 8] : &lkl[buf][kj][ph * 8];
        *(u16x8*)kd = kreg;
    };

    f32x4 acc[4][4];   // [i-tile][c-tile]
    const f32x4 fz = {0.f, 0.f, 0.f, 0.f};
#pragma unroll
    for (int a = 0; a < 4; a++)
#pragma unroll
        for (int c = 0; c < 4; c++) acc[a][c] = fz;

    float m_r[4], l_r[4];
#pragma unroll
    for (int r = 0; r < 4; r++) { m_r[r] = -3.0e38f; l_r[r] = 0.f; }

    const int c0 = w * 64;

    stage_load(0);
    stage_write(0);
    __syncthreads();

#pragma unroll 1
    for (int tt = 0; tt < NT; ++tt) {
        const int cur = tt & 1;
        const int nxt = cur ^ 1;
        const bool pre = (tt + 1 < NT);
        if (pre) stage_load(tt + 1);   // prefetch next K/V tile into regs

        // ---- scores for i-tile w: S[16 x 32], 3 MFMAs per 16x16 (hi/lo split)
        f32x4 s[2];
#pragma unroll
        for (int jt = 0; jt < 2; jt++) {
            const int j  = jt * 16 + cl;
            const int ph = (kg ^ ((j >> 2) & 3)) * 8;
            short8 kh = *(const short8*)&lkh[cur][j][ph];
            short8 kl = *(const short8*)&lkl[cur][j][ph];
            f32x4 sv = fz;
            sv = __builtin_amdgcn_mfma_f32_16x16x32_bf16(qh, kh, sv, 0, 0, 0);
            sv = __builtin_amdgcn_mfma_f32_16x16x32_bf16(qh, kl, sv, 0, 0, 0);
            sv = __builtin_amdgcn_mfma_f32_16x16x32_bf16(ql, kh, sv, 0, 0, 0);
            s[jt] = sv;
        }

        // ---- online softmax for rows kg*4+r (replicated over the 16 cl lanes)
        float f_r[4];
#pragma unroll
        for (int r = 0; r < 4; r++) {
            float tm = fmaxf(s[0][r], s[1][r]);
            tm = fmaxf(tm, __shfl_xor(tm, 1));
            tm = fmaxf(tm, __shfl_xor(tm, 2));
            tm = fmaxf(tm, __shfl_xor(tm, 4));
            tm = fmaxf(tm, __shfl_xor(tm, 8));
            float mn = fmaxf(m_r[r], tm);
            f_r[r] = exp2f((m_r[r] - mn) * LOG2E);
            m_r[r] = mn;
            float p0 = exp2f((s[0][r] - mn) * LOG2E);
            float p1 = exp2f((s[1][r] - mn) * LOG2E);
            const int row = kg * 4 + r;
            const int ph0 = (((cl >> 3)) ^ kg) * 8 + (cl & 7);
            const int ph1 = ((2 + (cl >> 3)) ^ kg) * 8 + (cl & 7);
            lp[w][row][ph0] = f2bf(p0);
            lp[w][row][ph1] = f2bf(p1);
            float psum = p0 + p1;
            psum += __shfl_xor(psum, 1);
            psum += __shfl_xor(psum, 2);
            psum += __shfl_xor(psum, 4);
            psum += __shfl_xor(psum, 8);
            l_r[r] = l_r[r] * f_r[r] + psum;
        }
        if (cl == 0) {
#pragma unroll
            for (int r = 0; r < 4; r++) lf[w][kg * 4 + r] = f_r[r];
        }

        if (pre) stage_write(nxt);   // vmcnt wait inserted by compiler
        __syncthreads();             // beta: lp/lf + next-tile LDS visible

        // ---- rescale accumulators (skip when no row max changed), then PV
        float ff[4][4];
#pragma unroll
        for (int it = 0; it < 4; it++)
#pragma unroll
            for (int r = 0; r < 4; r++) ff[it][r] = lf[it][kg * 4 + r];
        int ok = 1;
#pragma unroll
        for (int it = 0; it < 4; it++)
#pragma unroll
            for (int r = 0; r < 4; r++) ok &= (ff[it][r] == 1.f);
        if (!__all(ok)) {
#pragma unroll
            for (int it = 0; it < 4; it++)
#pragma unroll
                for (int ct = 0; ct < 4; ct++)
#pragma unroll
                    for (int r = 0; r < 4; r++) acc[it][ct][r] *= ff[it][r];
        }

        short8 pa[4];
        const int pph = (kg ^ ((cl >> 2) & 3)) * 8;
#pragma unroll
        for (int it = 0; it < 4; it++)
            pa[it] = *(const short8*)&lp[it][cl][pph];

#pragma unroll
        for (int ct = 0; ct < 4; ct++) {
            const int c  = c0 + ct * 16 + cl;
            const int ph = (kg ^ ((c >> 2) & 3)) * 8;
            short8 vb = *(const short8*)&lv[cur][c][ph];
#pragma unroll
            for (int it = 0; it < 4; it++)
                acc[it][ct] = __builtin_amdgcn_mfma_f32_16x16x32_bf16(pa[it], vb, acc[it][ct], 0, 0, 0);
        }
        __syncthreads();             // alpha: PV reads done before next overwrite
    }

    // ---- epilogue: 1/l, transpose via LDS, +x, coalesced float4 stores
    if (cl == 0) {
#pragma unroll
        for (int r = 0; r < 4; r++) lsc[w * 16 + kg * 4 + r] = 1.f / l_r[r];
    }
    __syncthreads();

    float* lt = ((float*)&lv[0][0][0]) + w * 320;   // per-wave 16x20 f32 staging

#pragma unroll 1
    for (int it = 0; it < 4; it++) {
        const f32x4 linv = *(const f32x4*)&lsc[it * 16 + (l & 3) * 4];
#pragma unroll 1
        for (int ct = 0; ct < 4; ct++) {
            __syncthreads();
#pragma unroll
            for (int r = 0; r < 4; r++)
                lt[cl * 20 + kg * 4 + r] = acc[it][ct][r];
            __syncthreads();
            const f32x4 vv = *(const f32x4*)&lt[(l >> 2) * 20 + (l & 3) * 4];
            const int c = c0 + ct * 16 + (l >> 2);
            const size_t base = ((size_t)(b * CDIM + c)) * NTOK + i0 + it * 16 + (l & 3) * 4;
            const f32x4 xv = *(const f32x4*)&x[base];
            f32x4 o;
#pragma unroll
            for (int ii = 0; ii < 4; ii++) o[ii] = vv[ii] * linv[ii] + xv[ii];
            *(f32x4*)&out[base] = o;
        }
    }
}

// ---------------------------------------------------------------------------
extern "C" void kernel_launch(void* const* d_in, const int* in_sizes, int n_in,
                              void* d_out, int out_size, void* d_ws, size_t ws_size,
                              hipStream_t stream) {
    const float* x  = (const float*)d_in[0];
    const float* Wq = (const float*)d_in[1];
    const float* bq = (const float*)d_in[2];
    const float* Wk = (const float*)d_in[3];
    const float* bk = (const float*)d_in[4];
    const float* Wv = (const float*)d_in[5];
    const float* bv = (const float*)d_in[6];
    float* out = (float*)d_out;

    u16* qhi = (u16*)d_ws;                              // [4][4096][32]
    u16* qlo = qhi + (size_t)4 * NTOK * 32;
    u16* khi = qlo + (size_t)4 * NTOK * 32;
    u16* klo = khi + (size_t)4 * NTOK * 32;
    u16* vbf = klo + (size_t)4 * NTOK * 32;             // [4][256][4096]

    proj_qk<<<dim3(64, 2, 4), 256, 0, stream>>>(x, Wq, bq, Wk, bk, qhi, qlo, khi, klo);
    proj_v<<<dim3(64, 4, 4), 256, 0, stream>>>(x, Wv, bv, vbf);
    attn_mfma<<<dim3(256), 256, 0, stream>>>(qhi, qlo, khi, klo, vbf, x, out);
}

// Round 3
// 436.014 us; speedup vs baseline: 1.9926x; 1.2536x over previous
//
#include <hip/hip_runtime.h>

typedef short short8 __attribute__((ext_vector_type(8)));
typedef float f32x4 __attribute__((ext_vector_type(4)));
typedef unsigned short u16;
typedef u16 u16x8 __attribute__((ext_vector_type(8)));
typedef unsigned int u32;
typedef u32 u32x4 __attribute__((ext_vector_type(4)));

#define NTOK 4096
#define CDIM 256
#define CQ 32
#define TQ 64
#define TJ 32
#define NT (NTOK / TJ)
#define LOG2E 1.44269504088896f

__device__ __forceinline__ u16 f2bf(float f) {
    unsigned u = __float_as_uint(f);
    unsigned r = (u + 0x7fffu + ((u >> 16) & 1u)) >> 16;   // RNE
    return (u16)r;
}
__device__ __forceinline__ float bf2f(u16 h) { return __uint_as_float(((unsigned)h) << 16); }
__device__ __forceinline__ u32 pk_bf16(float a, float b) {
    u32 w;
    asm("v_cvt_pk_bf16_f32 %0, %1, %2" : "=v"(w) : "v"(a), "v"(b));
    return w;
}

// ---------------------------------------------------------------------------
// Q/K projection (M=32): out token-major bf16 hi/lo [B][N][32]
// ---------------------------------------------------------------------------
__global__ __launch_bounds__(256, 2)
void proj_qk(const float* __restrict__ x,
             const float* __restrict__ Wq, const float* __restrict__ bq,
             const float* __restrict__ Wk, const float* __restrict__ bk,
             u16* __restrict__ qhi, u16* __restrict__ qlo,
             u16* __restrict__ khi, u16* __restrict__ klo) {
    __shared__ float xs[64][68];
    __shared__ float wsm[32][68];
    const int b  = blockIdx.z;
    const int n0 = blockIdx.x * 64;
    const int isK = blockIdx.y;
    const float* W    = isK ? Wk : Wq;
    const float* bias = isK ? bk : bq;
    u16* yh = isK ? khi : qhi;
    u16* yl = isK ? klo : qlo;
    const int t  = threadIdx.x;
    const int n  = t & 63;
    const int mg = t >> 6;
    const float* xb = x + (size_t)b * CDIM * NTOK;

    float acc[8];
#pragma unroll
    for (int i = 0; i < 8; i++) acc[i] = 0.f;

    for (int kc = 0; kc < CDIM; kc += 64) {
#pragma unroll
        for (int r = 0; r < 16; r++) {
            int idx = t + r * 256;
            xs[idx >> 6][idx & 63] = xb[(size_t)(kc + (idx >> 6)) * NTOK + n0 + (idx & 63)];
        }
#pragma unroll
        for (int r = 0; r < 8; r++) {
            int idx = t + r * 256;
            wsm[idx >> 6][idx & 63] = W[(size_t)(idx >> 6) * CDIM + kc + (idx & 63)];
        }
        __syncthreads();
#pragma unroll 8
        for (int c = 0; c < 64; c++) {
            float xv = xs[c][n];
#pragma unroll
            for (int mm = 0; mm < 8; mm++)
                acc[mm] = fmaf(wsm[mg * 8 + mm][c], xv, acc[mm]);
        }
        __syncthreads();
    }
    u16x8 h8, l8;
#pragma unroll
    for (int mm = 0; mm < 8; mm++) {
        float v = acc[mm] + bias[mg * 8 + mm];
        u16 h = f2bf(v);
        h8[mm] = h;
        l8[mm] = f2bf(v - bf2f(h));
    }
    const size_t base = ((size_t)(b * NTOK + n0 + n)) * 32 + mg * 8;
    *(u16x8*)&yh[base] = h8;
    *(u16x8*)&yl[base] = l8;
}

// ---------------------------------------------------------------------------
// V projection (M=256): out c-major bf16 [B][256][N]
// ---------------------------------------------------------------------------
__global__ __launch_bounds__(256, 2)
void proj_v(const float* __restrict__ x, const float* __restrict__ Wv,
            const float* __restrict__ bv, u16* __restrict__ vbf) {
    __shared__ float xs[64][68];
    __shared__ float wsm[64][68];
    const int b  = blockIdx.z;
    const int m0 = blockIdx.y * 64;
    const int n0 = blockIdx.x * 64;
    const int t  = threadIdx.x;
    const int n  = t & 63;
    const int mg = t >> 6;
    const float* xb = x + (size_t)b * CDIM * NTOK;

    float acc[16];
#pragma unroll
    for (int i = 0; i < 16; i++) acc[i] = 0.f;

    for (int kc = 0; kc < CDIM; kc += 64) {
#pragma unroll
        for (int r = 0; r < 16; r++) {
            int idx = t + r * 256;
            xs[idx >> 6][idx & 63] = xb[(size_t)(kc + (idx >> 6)) * NTOK + n0 + (idx & 63)];
        }
#pragma unroll
        for (int r = 0; r < 16; r++) {
            int idx = t + r * 256;
            wsm[idx >> 6][idx & 63] = Wv[(size_t)(m0 + (idx >> 6)) * CDIM + kc + (idx & 63)];
        }
        __syncthreads();
#pragma unroll 4
        for (int c = 0; c < 64; c++) {
            float xv = xs[c][n];
#pragma unroll
            for (int mm = 0; mm < 16; mm++)
                acc[mm] = fmaf(wsm[mg * 16 + mm][c], xv, acc[mm]);
        }
        __syncthreads();
    }
#pragma unroll
    for (int mm = 0; mm < 16; mm++) {
        int m = m0 + mg * 16 + mm;
        vbf[((size_t)(b * CDIM + m)) * NTOK + n0 + n] = f2bf(acc[mm] + bv[m]);
    }
}

// ---------------------------------------------------------------------------
// Fused flash attention, wave-independent structure.
// Wave w owns 16 queries (i0+w*16..+16) and ALL 256 output channels.
//   St[j][q] = mfma(A=K, B=Q)  (swapped)  -> lane: q=cl, j in-lane (kg*4+r, +16)
//   softmax: in-lane tree + shfl_xor(16,32); per-lane m/l; defer-max THR=8
//   P exchange to B-fragment: 8x ds_bpermute + cndmask
//   PV: D[c][q] = mfma(A=V, B=P), 16 c-tiles
// One barrier per iteration; double-buffered K/V; T14 staging split.
// ---------------------------------------------------------------------------
__global__ __launch_bounds__(256, 1)
void attn_mfma(const u16* __restrict__ qhi, const u16* __restrict__ qlo,
               const u16* __restrict__ khi, const u16* __restrict__ klo,
               const u16* __restrict__ vbf, const float* __restrict__ x,
               float* __restrict__ out) {
    __shared__ __attribute__((aligned(16))) u16 lkh[2][TJ][32];
    __shared__ __attribute__((aligned(16))) u16 lkl[2][TJ][32];
    __shared__ __attribute__((aligned(16))) u16 lv[2][CDIM][TJ];
    __shared__ __attribute__((aligned(16))) float lt[4][16][20];

    const int lin = blockIdx.x;
    const int b  = (lin >> 1) & 3;
    const int qb = ((lin & 1) << 5) | (lin >> 3);
    const int i0 = qb * TQ;
    const int t  = threadIdx.x;
    const int w  = t >> 6;
    const int l  = t & 63;
    const int cl = l & 15;
    const int kg = l >> 4;

    // Q B-fragments: lane holds Q[i0+w*16+cl][kg*8..+8]
    const int iq = i0 + w * 16 + cl;
    const short8 qh = *(const short8*)&qhi[((size_t)(b * NTOK + iq)) * 32 + kg * 8];
    const short8 ql = *(const short8*)&qlo[((size_t)(b * NTOK + iq)) * 32 + kg * 8];

    // staging sources (identical to verified round-2 scheme)
    const u16* vsrc = &vbf[((size_t)(b * CDIM + t)) * NTOK];
    const int kj  = (t & 127) >> 2;
    const int kch = t & 3;
    const u16* ksrcbase = (t < 128) ? khi : klo;
    const u16* ksrc = &ksrcbase[((size_t)(b * NTOK + kj)) * 32 + kch * 8];

    u16x8 vreg[4];
    u16x8 kreg;

    auto stage_load = [&](int tt) {
        const int j0 = tt * TJ;
#pragma unroll
        for (int ch = 0; ch < 4; ch++)
            vreg[ch] = *(const u16x8*)&vsrc[j0 + ch * 8];
        kreg = *(const u16x8*)&ksrc[(size_t)j0 * 32];
    };
    auto stage_write = [&](int buf) {
#pragma unroll
        for (int ch = 0; ch < 4; ch++) {
            int ph = ch ^ ((t >> 2) & 3);
            *(u16x8*)&lv[buf][t][ph * 8] = vreg[ch];
        }
        int ph = kch ^ ((kj >> 2) & 3);
        u16* kd = (t < 128) ? &lkh[buf][kj][ph * 8] : &lkl[buf][kj][ph * 8];
        *(u16x8*)kd = kreg;
    };

    f32x4 acc[16];   // D[c][q]: c = ct*16 + kg*4 + r, q = cl
    const f32x4 fz = {0.f, 0.f, 0.f, 0.f};
#pragma unroll
    for (int ct = 0; ct < 16; ct++) acc[ct] = fz;

    float m_r = -1.0e30f, l_r = 0.f;

    // bpermute byte addresses for the P exchange
    const int a0 = (((kg << 1) & 3) * 16 + cl) * 4;
    const int a1 = ((((kg << 1) + 1) & 3) * 16 + cl) * 4;
    const bool lo2 = (kg < 2);

    stage_load(0);
    stage_write(0);
    __syncthreads();

#pragma unroll 1
    for (int tt = 0; tt < NT; ++tt) {
        const int cur = tt & 1;
        const int nxt = cur ^ 1;
        const bool pre = (tt + 1 < NT);
        if (pre) stage_load(tt + 1);   // issue global loads early (T14)

        // ---- scores (swapped): St[j][q], lane q=cl, rows j=kg*4+r (+16*jt)
        f32x4 s0 = fz, s1 = fz;
        {
            const int j0r = cl;        // jt=0 row
            const int ph0 = (kg ^ ((j0r >> 2) & 3)) * 8;
            short8 kh = *(const short8*)&lkh[cur][j0r][ph0];
            short8 kl = *(const short8*)&lkl[cur][j0r][ph0];
            s0 = __builtin_amdgcn_mfma_f32_16x16x32_bf16(kh, qh, s0, 0, 0, 0);
            s0 = __builtin_amdgcn_mfma_f32_16x16x32_bf16(kl, qh, s0, 0, 0, 0);
            s0 = __builtin_amdgcn_mfma_f32_16x16x32_bf16(kh, ql, s0, 0, 0, 0);
        }
        {
            const int j1r = 16 + cl;   // jt=1 row
            const int ph1 = (kg ^ ((j1r >> 2) & 3)) * 8;
            short8 kh = *(const short8*)&lkh[cur][j1r][ph1];
            short8 kl = *(const short8*)&lkl[cur][j1r][ph1];
            s1 = __builtin_amdgcn_mfma_f32_16x16x32_bf16(kh, qh, s1, 0, 0, 0);
            s1 = __builtin_amdgcn_mfma_f32_16x16x32_bf16(kl, qh, s1, 0, 0, 0);
            s1 = __builtin_amdgcn_mfma_f32_16x16x32_bf16(kh, ql, s1, 0, 0, 0);
        }

        // ---- in-lane softmax (per-lane q = cl)
        float tmax = fmaxf(fmaxf(fmaxf(s0[0], s0[1]), fmaxf(s0[2], s0[3])),
                           fmaxf(fmaxf(s1[0], s1[1]), fmaxf(s1[2], s1[3])));
        tmax = fmaxf(tmax, __shfl_xor(tmax, 16));
        tmax = fmaxf(tmax, __shfl_xor(tmax, 32));

        if (__any(tmax > m_r + 8.f)) {          // rescale event (defer-max)
            float mn = fmaxf(m_r, tmax);
            float f  = exp2f((m_r - mn) * LOG2E);
            m_r = mn;
            l_r *= f;
#pragma unroll
            for (int ct = 0; ct < 16; ct++) acc[ct] *= f;
        }
        const float mm = m_r * LOG2E;
        float p00 = exp2f(fmaf(s0[0], LOG2E, -mm));
        float p01 = exp2f(fmaf(s0[1], LOG2E, -mm));
        float p02 = exp2f(fmaf(s0[2], LOG2E, -mm));
        float p03 = exp2f(fmaf(s0[3], LOG2E, -mm));
        float p10 = exp2f(fmaf(s1[0], LOG2E, -mm));
        float p11 = exp2f(fmaf(s1[1], LOG2E, -mm));
        float p12 = exp2f(fmaf(s1[2], LOG2E, -mm));
        float p13 = exp2f(fmaf(s1[3], LOG2E, -mm));

        float psum = ((p00 + p01) + (p02 + p03)) + ((p10 + p11) + (p12 + p13));
        psum += __shfl_xor(psum, 16);
        psum += __shfl_xor(psum, 32);
        l_r += psum;

        // ---- pack to bf16 pairs, exchange to B-fragment (k = j)
        u32 w0 = pk_bf16(p00, p01);   // j = 4kg+0, 4kg+1
        u32 w1 = pk_bf16(p02, p03);   // j = 4kg+2, 4kg+3
        u32 w2 = pk_bf16(p10, p11);   // j = 16+4kg+0, +1
        u32 w3 = pk_bf16(p12, p13);   // j = 16+4kg+2, +3
        u32 y0a = __builtin_amdgcn_ds_bpermute(a0, w0);
        u32 y0b = __builtin_amdgcn_ds_bpermute(a0, w2);
        u32 y1a = __builtin_amdgcn_ds_bpermute(a0, w1);
        u32 y1b = __builtin_amdgcn_ds_bpermute(a0, w3);
        u32 y2a = __builtin_amdgcn_ds_bpermute(a1, w0);
        u32 y2b = __builtin_amdgcn_ds_bpermute(a1, w2);
        u32 y3a = __builtin_amdgcn_ds_bpermute(a1, w1);
        u32 y3b = __builtin_amdgcn_ds_bpermute(a1, w3);
        u32x4 bw;
        bw[0] = lo2 ? y0a : y0b;   // k = kg*8+0,1
        bw[1] = lo2 ? y1a : y1b;   // k = kg*8+2,3
        bw[2] = lo2 ? y2a : y2b;   // k = kg*8+4,5
        bw[3] = lo2 ? y3a : y3b;   // k = kg*8+6,7
        const short8 pfrag = __builtin_bit_cast(short8, bw);

        // ---- PV: acc[ct] += V-tile * P  (A=V: row c=cl, k=j; B=P: col q=cl)
#pragma unroll
        for (int ct = 0; ct < 16; ct++) {
            const int c  = ct * 16 + cl;
            const int ph = (kg ^ ((c >> 2) & 3)) * 8;
            short8 vb = *(const short8*)&lv[cur][c][ph];
            acc[ct] = __builtin_amdgcn_mfma_f32_16x16x32_bf16(vb, pfrag, acc[ct], 0, 0, 0);
        }

        if (pre) stage_write(nxt);
        __syncthreads();
    }

    // ---- epilogue: /l, transpose via per-wave LDS tile, +x, coalesced store
    const float linv = 1.f / l_r;          // lane's q = cl
    const int c_r = l >> 2;
    const int q0  = (l & 3) * 4;
#pragma unroll 1
    for (int ct = 0; ct < 16; ct++) {
#pragma unroll
        for (int r = 0; r < 4; r++)
            lt[w][kg * 4 + r][cl] = acc[ct][r] * linv;
        __syncthreads();
        const f32x4 vv = *(const f32x4*)&lt[w][c_r][q0];
        const int c = ct * 16 + c_r;
        const size_t base = ((size_t)(b * CDIM + c)) * NTOK + i0 + w * 16 + q0;
        const f32x4 xv = *(const f32x4*)&x[base];
        f32x4 o;
#pragma unroll
        for (int ii = 0; ii < 4; ii++) o[ii] = vv[ii] + xv[ii];
        *(f32x4*)&out[base] = o;
        __syncthreads();
    }
}

// ---------------------------------------------------------------------------
extern "C" void kernel_launch(void* const* d_in, const int* in_sizes, int n_in,
                              void* d_out, int out_size, void* d_ws, size_t ws_size,
                              hipStream_t stream) {
    const float* x  = (const float*)d_in[0];
    const float* Wq = (const float*)d_in[1];
    const float* bq = (const float*)d_in[2];
    const float* Wk = (const float*)d_in[3];
    const float* bk = (const float*)d_in[4];
    const float* Wv = (const float*)d_in[5];
    const float* bv = (const float*)d_in[6];
    float* out = (float*)d_out;

    u16* qhi = (u16*)d_ws;                              // [4][4096][32]
    u16* qlo = qhi + (size_t)4 * NTOK * 32;
    u16* khi = qlo + (size_t)4 * NTOK * 32;
    u16* klo = khi + (size_t)4 * NTOK * 32;
    u16* vbf = klo + (size_t)4 * NTOK * 32;             // [4][256][4096]

    proj_qk<<<dim3(64, 2, 4), 256, 0, stream>>>(x, Wq, bq, Wk, bk, qhi, qlo, khi, klo);
    proj_v<<<dim3(64, 4, 4), 256, 0, stream>>>(x, Wv, bv, vbf);
    attn_mfma<<<dim3(256), 256, 0, stream>>>(qhi, qlo, khi, klo, vbf, x, out);
}

// Round 4
// 247.104 us; speedup vs baseline: 3.5159x; 1.7645x over previous
//
#include <hip/hip_runtime.h>

typedef short short8 __attribute__((ext_vector_type(8)));
typedef float f32x4 __attribute__((ext_vector_type(4)));
typedef unsigned short u16;
typedef u16 u16x8 __attribute__((ext_vector_type(8)));
typedef unsigned int u32;
typedef u32 u32x4 __attribute__((ext_vector_type(4)));

#define NTOK 4096
#define CDIM 256
#define TQ 64
#define TJ 32
#define NT (NTOK / TJ)
#define LOG2E 1.44269504088896f

__device__ __forceinline__ u16 f2bf(float f) {
    unsigned u = __float_as_uint(f);
    unsigned r = (u + 0x7fffu + ((u >> 16) & 1u)) >> 16;   // RNE
    return (u16)r;
}
__device__ __forceinline__ float bf2f(u16 h) { return __uint_as_float(((unsigned)h) << 16); }
__device__ __forceinline__ u32 pk_bf16(float a, float b) {
    u32 w;
    asm("v_cvt_pk_bf16_f32 %0, %1, %2" : "=v"(w) : "v"(a), "v"(b));
    return w;
}

// ---------------------------------------------------------------------------
// Q/K projection (M=32): out token-major bf16 hi/lo [B][N][32]
// ---------------------------------------------------------------------------
__global__ __launch_bounds__(256, 2)
void proj_qk(const float* __restrict__ x,
             const float* __restrict__ Wq, const float* __restrict__ bq,
             const float* __restrict__ Wk, const float* __restrict__ bk,
             u16* __restrict__ qhi, u16* __restrict__ qlo,
             u16* __restrict__ khi, u16* __restrict__ klo) {
    __shared__ float xs[64][68];
    __shared__ float wsm[32][68];
    const int b  = blockIdx.z;
    const int n0 = blockIdx.x * 64;
    const int isK = blockIdx.y;
    const float* W    = isK ? Wk : Wq;
    const float* bias = isK ? bk : bq;
    u16* yh = isK ? khi : qhi;
    u16* yl = isK ? klo : qlo;
    const int t  = threadIdx.x;
    const int n  = t & 63;
    const int mg = t >> 6;
    const float* xb = x + (size_t)b * CDIM * NTOK;

    float acc[8];
#pragma unroll
    for (int i = 0; i < 8; i++) acc[i] = 0.f;

    for (int kc = 0; kc < CDIM; kc += 64) {
#pragma unroll
        for (int r = 0; r < 16; r++) {
            int idx = t + r * 256;
            xs[idx >> 6][idx & 63] = xb[(size_t)(kc + (idx >> 6)) * NTOK + n0 + (idx & 63)];
        }
#pragma unroll
        for (int r = 0; r < 8; r++) {
            int idx = t + r * 256;
            wsm[idx >> 6][idx & 63] = W[(size_t)(idx >> 6) * CDIM + kc + (idx & 63)];
        }
        __syncthreads();
#pragma unroll 8
        for (int c = 0; c < 64; c++) {
            float xv = xs[c][n];
#pragma unroll
            for (int mm = 0; mm < 8; mm++)
                acc[mm] = fmaf(wsm[mg * 8 + mm][c], xv, acc[mm]);
        }
        __syncthreads();
    }
    u16x8 h8, l8;
#pragma unroll
    for (int mm = 0; mm < 8; mm++) {
        float v = acc[mm] + bias[mg * 8 + mm];
        u16 h = f2bf(v);
        h8[mm] = h;
        l8[mm] = f2bf(v - bf2f(h));
    }
    const size_t base = ((size_t)(b * NTOK + n0 + n)) * 32 + mg * 8;
    *(u16x8*)&yh[base] = h8;
    *(u16x8*)&yl[base] = l8;
}

// ---------------------------------------------------------------------------
// V projection (M=256): out c-major bf16 [B][256][N]
// ---------------------------------------------------------------------------
__global__ __launch_bounds__(256, 2)
void proj_v(const float* __restrict__ x, const float* __restrict__ Wv,
            const float* __restrict__ bv, u16* __restrict__ vbf) {
    __shared__ float xs[64][68];
    __shared__ float wsm[64][68];
    const int b  = blockIdx.z;
    const int m0 = blockIdx.y * 64;
    const int n0 = blockIdx.x * 64;
    const int t  = threadIdx.x;
    const int n  = t & 63;
    const int mg = t >> 6;
    const float* xb = x + (size_t)b * CDIM * NTOK;

    float acc[16];
#pragma unroll
    for (int i = 0; i < 16; i++) acc[i] = 0.f;

    for (int kc = 0; kc < CDIM; kc += 64) {
#pragma unroll
        for (int r = 0; r < 16; r++) {
            int idx = t + r * 256;
            xs[idx >> 6][idx & 63] = xb[(size_t)(kc + (idx >> 6)) * NTOK + n0 + (idx & 63)];
        }
#pragma unroll
        for (int r = 0; r < 16; r++) {
            int idx = t + r * 256;
            wsm[idx >> 6][idx & 63] = Wv[(size_t)(m0 + (idx >> 6)) * CDIM + kc + (idx & 63)];
        }
        __syncthreads();
#pragma unroll 4
        for (int c = 0; c < 64; c++) {
            float xv = xs[c][n];
#pragma unroll
            for (int mm = 0; mm < 16; mm++)
                acc[mm] = fmaf(wsm[mg * 16 + mm][c], xv, acc[mm]);
        }
        __syncthreads();
    }
#pragma unroll
    for (int mm = 0; mm < 16; mm++) {
        int m = m0 + mg * 16 + mm;
        vbf[((size_t)(b * CDIM + m)) * NTOK + n0 + n] = f2bf(acc[mm] + bv[m]);
    }
}

// ---------------------------------------------------------------------------
// Fused flash attention. Block = 256 threads = 4 waves, handles TQ=64 queries
// and ONE HALF (h) of the 256 channels. Wave w: q-tile w (16 q), 128 c.
// acc[8] = 32 VGPRs/thread (spill fix). Grid 512 -> 2 blocks/CU.
//   St[j][q] = mfma(A=K, B=Q); in-lane softmax + shfl_xor(16,32); defer-max
//   P -> B-fragment via 8x ds_bpermute; PV: D[c][q] = mfma(A=V, B=P)
// ---------------------------------------------------------------------------
__global__ __launch_bounds__(256, 2)
void attn_mfma(const u16* __restrict__ qhi, const u16* __restrict__ qlo,
               const u16* __restrict__ khi, const u16* __restrict__ klo,
               const u16* __restrict__ vbf, const float* __restrict__ x,
               float* __restrict__ out) {
    __shared__ __attribute__((aligned(16))) u16 lkh[2][TJ][32];
    __shared__ __attribute__((aligned(16))) u16 lkl[2][TJ][32];
    __shared__ __attribute__((aligned(16))) u16 lv[2][128][TJ];
    __shared__ __attribute__((aligned(16))) float lt[4][16][20];

    // XCD decode: p = lin&7 is the XCD under round-robin dispatch.
    // (b,h) fixed per XCD -> V-half (1MB) + K (2MB) resident in that L2.
    const int lin = blockIdx.x;
    const int p  = lin & 7;
    const int b  = p >> 1;
    const int h  = p & 1;
    const int qb = lin >> 3;          // 0..63
    const int i0 = qb * TQ;
    const int t  = threadIdx.x;
    const int w  = t >> 6;
    const int l  = t & 63;
    const int cl = l & 15;
    const int kg = l >> 4;

    // Q B-fragments: lane holds Q[i0+w*16+cl][kg*8..+8]
    const int iq = i0 + w * 16 + cl;
    const short8 qh = *(const short8*)&qhi[((size_t)(b * NTOK + iq)) * 32 + kg * 8];
    const short8 ql = *(const short8*)&qlo[((size_t)(b * NTOK + iq)) * 32 + kg * 8];

    // staging sources: V half (128 rows, 2 chunks/thread), K hi/lo as before
    const int vc   = t & 127;
    const int vch0 = (t >> 7) * 2;
    const u16* vsrc = &vbf[((size_t)(b * CDIM + h * 128 + vc)) * NTOK + vch0 * 8];
    const int kj  = (t & 127) >> 2;
    const int kch = t & 3;
    const u16* ksrcbase = (t < 128) ? khi : klo;
    const u16* ksrc = &ksrcbase[((size_t)(b * NTOK + kj)) * 32 + kch * 8];

    u16x8 vreg0, vreg1, kreg;

    auto stage_load = [&](int tt) {
        const int j0 = tt * TJ;
        vreg0 = *(const u16x8*)&vsrc[j0];
        vreg1 = *(const u16x8*)&vsrc[j0 + 8];
        kreg  = *(const u16x8*)&ksrc[(size_t)j0 * 32];
    };
    auto stage_write = [&](int buf) {
        const int sw = (vc >> 2) & 3;
        *(u16x8*)&lv[buf][vc][((vch0)     ^ sw) * 8] = vreg0;
        *(u16x8*)&lv[buf][vc][((vch0 + 1) ^ sw) * 8] = vreg1;
        int ph = kch ^ ((kj >> 2) & 3);
        u16* kd = (t < 128) ? &lkh[buf][kj][ph * 8] : &lkl[buf][kj][ph * 8];
        *(u16x8*)kd = kreg;
    };

    f32x4 acc[8];   // D[c][q]: local c-row = ct*16 + kg*4 + r, q = cl
    const f32x4 fz = {0.f, 0.f, 0.f, 0.f};
#pragma unroll
    for (int ct = 0; ct < 8; ct++) acc[ct] = fz;

    float m_r = -1.0e30f, l_r = 0.f;

    // bpermute byte addresses for the P exchange
    const int a0 = (((kg << 1) & 3) * 16 + cl) * 4;
    const int a1 = ((((kg << 1) + 1) & 3) * 16 + cl) * 4;
    const bool lo2 = (kg < 2);

    stage_load(0);
    stage_write(0);
    __syncthreads();

#pragma unroll 2
    for (int tt = 0; tt < NT; ++tt) {
        const int cur = tt & 1;
        const int nxt = cur ^ 1;
        const bool pre = (tt + 1 < NT);
        if (pre) stage_load(tt + 1);   // issue global loads early (T14)

        // ---- scores (swapped): St[j][q], lane q=cl, rows j=kg*4+r (+16*jt)
        f32x4 s0 = fz, s1 = fz;
        {
            const int j0r = cl;
            const int ph0 = (kg ^ ((j0r >> 2) & 3)) * 8;
            short8 kh = *(const short8*)&lkh[cur][j0r][ph0];
            short8 kl = *(const short8*)&lkl[cur][j0r][ph0];
            s0 = __builtin_amdgcn_mfma_f32_16x16x32_bf16(kh, qh, s0, 0, 0, 0);
            s0 = __builtin_amdgcn_mfma_f32_16x16x32_bf16(kl, qh, s0, 0, 0, 0);
            s0 = __builtin_amdgcn_mfma_f32_16x16x32_bf16(kh, ql, s0, 0, 0, 0);
        }
        {
            const int j1r = 16 + cl;
            const int ph1 = (kg ^ ((j1r >> 2) & 3)) * 8;
            short8 kh = *(const short8*)&lkh[cur][j1r][ph1];
            short8 kl = *(const short8*)&lkl[cur][j1r][ph1];
            s1 = __builtin_amdgcn_mfma_f32_16x16x32_bf16(kh, qh, s1, 0, 0, 0);
            s1 = __builtin_amdgcn_mfma_f32_16x16x32_bf16(kl, qh, s1, 0, 0, 0);
            s1 = __builtin_amdgcn_mfma_f32_16x16x32_bf16(kh, ql, s1, 0, 0, 0);
        }

        // ---- in-lane softmax (per-lane q = cl)
        float tmax = fmaxf(fmaxf(fmaxf(s0[0], s0[1]), fmaxf(s0[2], s0[3])),
                           fmaxf(fmaxf(s1[0], s1[1]), fmaxf(s1[2], s1[3])));
        tmax = fmaxf(tmax, __shfl_xor(tmax, 16));
        tmax = fmaxf(tmax, __shfl_xor(tmax, 32));

        if (__any(tmax > m_r + 8.f)) {          // defer-max rescale event
            float mn = fmaxf(m_r, tmax);
            float f  = exp2f((m_r - mn) * LOG2E);
            m_r = mn;
            l_r *= f;
#pragma unroll
            for (int ct = 0; ct < 8; ct++) acc[ct] *= f;
        }
        const float mm = m_r * LOG2E;
        float p00 = exp2f(fmaf(s0[0], LOG2E, -mm));
        float p01 = exp2f(fmaf(s0[1], LOG2E, -mm));
        float p02 = exp2f(fmaf(s0[2], LOG2E, -mm));
        float p03 = exp2f(fmaf(s0[3], LOG2E, -mm));
        float p10 = exp2f(fmaf(s1[0], LOG2E, -mm));
        float p11 = exp2f(fmaf(s1[1], LOG2E, -mm));
        float p12 = exp2f(fmaf(s1[2], LOG2E, -mm));
        float p13 = exp2f(fmaf(s1[3], LOG2E, -mm));

        float psum = ((p00 + p01) + (p02 + p03)) + ((p10 + p11) + (p12 + p13));
        psum += __shfl_xor(psum, 16);
        psum += __shfl_xor(psum, 32);
        l_r += psum;

        // ---- pack to bf16 pairs, exchange to B-fragment (k = j)
        u32 w0 = pk_bf16(p00, p01);
        u32 w1 = pk_bf16(p02, p03);
        u32 w2 = pk_bf16(p10, p11);
        u32 w3 = pk_bf16(p12, p13);
        u32 y0a = __builtin_amdgcn_ds_bpermute(a0, w0);
        u32 y0b = __builtin_amdgcn_ds_bpermute(a0, w2);
        u32 y1a = __builtin_amdgcn_ds_bpermute(a0, w1);
        u32 y1b = __builtin_amdgcn_ds_bpermute(a0, w3);
        u32 y2a = __builtin_amdgcn_ds_bpermute(a1, w0);
        u32 y2b = __builtin_amdgcn_ds_bpermute(a1, w2);
        u32 y3a = __builtin_amdgcn_ds_bpermute(a1, w1);
        u32 y3b = __builtin_amdgcn_ds_bpermute(a1, w3);
        u32x4 bw;
        bw[0] = lo2 ? y0a : y0b;
        bw[1] = lo2 ? y1a : y1b;
        bw[2] = lo2 ? y2a : y2b;
        bw[3] = lo2 ? y3a : y3b;
        const short8 pfrag = __builtin_bit_cast(short8, bw);

        // ---- PV over this block's c-half: 8 c-tiles
#pragma unroll
        for (int ct = 0; ct < 8; ct++) {
            const int row = ct * 16 + cl;
            const int ph  = (kg ^ ((row >> 2) & 3)) * 8;
            short8 vb = *(const short8*)&lv[cur][row][ph];
            acc[ct] = __builtin_amdgcn_mfma_f32_16x16x32_bf16(vb, pfrag, acc[ct], 0, 0, 0);
        }

        if (pre) stage_write(nxt);
        __syncthreads();
    }

    // ---- epilogue: /l, per-wave LDS transpose, +x, coalesced f32x4 stores
    const float linv = 1.f / l_r;
    const int c_r = l >> 2;
    const int q0  = (l & 3) * 4;
#pragma unroll 1
    for (int ct = 0; ct < 8; ct++) {
#pragma unroll
        for (int r = 0; r < 4; r++)
            lt[w][kg * 4 + r][cl] = acc[ct][r] * linv;
        __syncthreads();
        const f32x4 vv = *(const f32x4*)&lt[w][c_r][q0];
        const int c = h * 128 + ct * 16 + c_r;
        const size_t base = ((size_t)(b * CDIM + c)) * NTOK + i0 + w * 16 + q0;
        const f32x4 xv = *(const f32x4*)&x[base];
        f32x4 o;
#pragma unroll
        for (int ii = 0; ii < 4; ii++) o[ii] = vv[ii] + xv[ii];
        *(f32x4*)&out[base] = o;
        __syncthreads();
    }
}

// ---------------------------------------------------------------------------
extern "C" void kernel_launch(void* const* d_in, const int* in_sizes, int n_in,
                              void* d_out, int out_size, void* d_ws, size_t ws_size,
                              hipStream_t stream) {
    const float* x  = (const float*)d_in[0];
    const float* Wq = (const float*)d_in[1];
    const float* bq = (const float*)d_in[2];
    const float* Wk = (const float*)d_in[3];
    const float* bk = (const float*)d_in[4];
    const float* Wv = (const float*)d_in[5];
    const float* bv = (const float*)d_in[6];
    float* out = (float*)d_out;

    u16* qhi = (u16*)d_ws;                              // [4][4096][32]
    u16* qlo = qhi + (size_t)4 * NTOK * 32;
    u16* khi = qlo + (size_t)4 * NTOK * 32;
    u16* klo = khi + (size_t)4 * NTOK * 32;
    u16* vbf = klo + (size_t)4 * NTOK * 32;             // [4][256][4096]

    proj_qk<<<dim3(64, 2, 4), 256, 0, stream>>>(x, Wq, bq, Wk, bk, qhi, qlo, khi, klo);
    proj_v<<<dim3(64, 4, 4), 256, 0, stream>>>(x, Wv, bv, vbf);
    attn_mfma<<<dim3(512), 256, 0, stream>>>(qhi, qlo, khi, klo, vbf, x, out);
}